// Round 12
// baseline (575.574 us; speedup 1.0000x reference)
//
#include <hip/hip_runtime.h>

typedef __bf16 bf16;
using short8 = __attribute__((ext_vector_type(8))) __bf16;
using f32x4  = __attribute__((ext_vector_type(4))) float;

#define N_TOK 4128
#define QD    320
#define DH    40
#define W_VIS 4096
#define SPLITS 4
#define N_SP  4224
#define BSTRIDE 344   /* LDS B-stage stride: 16B-aligned rows, 2-way (free) frag reads */

#if __has_builtin(__builtin_amdgcn_exp2f)
#define EXP2F(x) __builtin_amdgcn_exp2f(x)
#else
#define EXP2F(x) exp2f(x)
#endif

__device__ __forceinline__ float loadS(const void* b, long i, bool isbf) {
  return isbf ? (float)((const bf16*)b)[i] : ((const float*)b)[i];
}
__device__ __forceinline__ unsigned short bfbits(float x) {
  bf16 h = (bf16)x;
  return __builtin_bit_cast(unsigned short, h);
}

// per-block dtype sniff: att is {0,1}; as fp32 its even halfwords are all 0;
// as bf16 ~15% are 0x3F80. 256 samples -> P(miss) ~ 0.85^256 ~ 4e-19.
__device__ __forceinline__ bool blk_sniff(const unsigned short* att_h, int nthr) {
  __shared__ int s;
  if (threadIdx.x == 0) s = 0;
  __syncthreads();
  int step = 8192 / nthr;
  if (att_h[threadIdx.x * step] != 0) atomicOr(&s, 1);
  __syncthreads();
  return s != 0;
}

// dtype-aware A-fragment (8 contiguous k at row) -> bf16 bits
__device__ __forceinline__ short8 load_afrag(const void* x, long row, int koff, bool isbf) {
  if (isbf) return *(const short8*)((const bf16*)x + row * QD + koff);
  const float* f = (const float*)x + row * QD + koff;
  float4 a = *(const float4*)f, b = *(const float4*)(f + 4);
  union { short8 v; unsigned short e[8]; } u;
  u.e[0] = bfbits(a.x); u.e[1] = bfbits(a.y); u.e[2] = bfbits(a.z); u.e[3] = bfbits(a.w);
  u.e[4] = bfbits(b.x); u.e[5] = bfbits(b.y); u.e[6] = bfbits(b.z); u.e[7] = bfbits(b.w);
  return u.v;
}

// ---------- mega QKV: masks+ones (by==15) | GEMM with LDS-staged B from raw W,
// epilogue writes q row-major + kswz/vswz fragment layouts straight from LDS C ----------
__global__ __launch_bounds__(256) void qkv_mega(
    const void* __restrict__ x, const void* __restrict__ att,
    const void* __restrict__ Wq, const void* __restrict__ Wk, const void* __restrict__ Wv,
    bf16* __restrict__ q, bf16* __restrict__ kswz, bf16* __restrict__ vswz,
    unsigned short* __restrict__ awA, unsigned short* __restrict__ bwB) {
  bool isbf = blk_sniff((const unsigned short*)att, 256);
  if (blockIdx.y == 15) {      // ---- util slice: mask words + vswz d=40..47 ones/zeros
    int flat = blockIdx.x * 256 + threadIdx.x;
    if (flat < N_SP) {
      int t = flat;
      unsigned int Aw = 0u, Bw = 0u;
      if (t < N_TOK) {
        unsigned int b9 = 0u; bool forced = false;
        if (t < W_VIS) {
#pragma unroll
          for (int o = 0; o < 8; ++o)
            if (loadS(att, o * W_VIS + t, isbf) != 0.0f) b9 |= (1u << o);
        } else {
          int g = t - W_VIS;
          int rep = g >> 3, oo = g & 7;
          forced = (rep == 1 || rep == 2);
          b9 = 0x100u | (forced ? 0u : (1u << oo));
        }
        Aw = b9 | (forced ? 0x200u : 0u) | 0x400u;
        Bw = b9 | (forced ? 0x400u : 0u) | 0x200u;
      }
      awA[t] = (unsigned short)Aw;
      bwB[t] = (unsigned short)Bw;
    } else if (flat - N_SP < 8320) {
      int idx = flat - N_SP;
#pragma unroll
      for (int m = 0; m < 4; ++m) {
        int t = idx * 4 + m;           // 0..33279
        int li8 = t & 7; int t2 = t >> 3;
        int q2 = t2 & 3; t2 >>= 2;
        int ksv = t2 & 1; t2 >>= 1;
        int kt = t2 % 65, h = t2 / 65;
        bf16 val = (li8 == 0) ? (bf16)1.0f : (bf16)0.0f;   // d=40 ones (l via MFMA)
        short8 v8 = {val, val, val, val, val, val, val, val};
        long base = (((long)h * 65 + kt) * 6 + ksv * 3 + 2) * 512;
        *(short8*)(vswz + base + (q2 * 16 + 8 + li8) * 8) = v8;
      }
    }
    return;
  }
  __shared__ unsigned short lbuf[64 * BSTRIDE];   // B-stage; aliased as C-tile later
  int m0 = blockIdx.x * 64;
  int ng = blockIdx.y * 64;
  int wsel = ng / 320;                 // 0=q 1=k 2=v
  int n_in = ng % 320;
  const void* W = wsel == 0 ? Wq : wsel == 1 ? Wk : Wv;
  // ---- stage B: W[k][n] -> lbuf[n_rel][k] bf16 (coalesced global reads)
  {
    int krow0 = threadIdx.x >> 2;
    int c16 = (threadIdx.x & 3) * 16;
#pragma unroll
    for (int it = 0; it < 5; ++it) {
      int kk = it * 64 + krow0;
      if (!isbf) {
        const float* wp = (const float*)W + (long)kk * QD + n_in + c16;
        float4 f0 = *(const float4*)wp,     f1 = *(const float4*)(wp + 4);
        float4 f2 = *(const float4*)(wp + 8), f3 = *(const float4*)(wp + 12);
        float fv[16] = {f0.x, f0.y, f0.z, f0.w, f1.x, f1.y, f1.z, f1.w,
                        f2.x, f2.y, f2.z, f2.w, f3.x, f3.y, f3.z, f3.w};
#pragma unroll
        for (int j = 0; j < 16; ++j) lbuf[(c16 + j) * BSTRIDE + kk] = bfbits(fv[j]);
      } else {
        const unsigned short* wp = (const unsigned short*)W + (long)kk * QD + n_in + c16;
#pragma unroll
        for (int j4 = 0; j4 < 4; ++j4) {
          ushort4 u4 = *(const ushort4*)(wp + j4 * 4);
          lbuf[(c16 + j4 * 4 + 0) * BSTRIDE + kk] = u4.x;
          lbuf[(c16 + j4 * 4 + 1) * BSTRIDE + kk] = u4.y;
          lbuf[(c16 + j4 * 4 + 2) * BSTRIDE + kk] = u4.z;
          lbuf[(c16 + j4 * 4 + 3) * BSTRIDE + kk] = u4.w;
        }
      }
    }
  }
  __syncthreads();
  int wv = threadIdx.x >> 6, lane = threadIdx.x & 63;
  int quad = lane >> 4, li = lane & 15;
  int wm = wv >> 1, wn = wv & 1;
  f32x4 acc[2][2];
#pragma unroll
  for (int a = 0; a < 2; a++)
#pragma unroll
    for (int b = 0; b < 2; b++) acc[a][b] = (f32x4){0.f, 0.f, 0.f, 0.f};
#pragma unroll
  for (int ks = 0; ks < 10; ++ks) {
    short8 af[2], bfrag[2];
#pragma unroll
    for (int mt = 0; mt < 2; ++mt) {
      long r = m0 + wm * 32 + mt * 16 + li;
      if (r > N_TOK - 1) r = N_TOK - 1;
      af[mt] = load_afrag(x, r, ks * 32 + quad * 8, isbf);
    }
#pragma unroll
    for (int nt = 0; nt < 2; ++nt) {
      int nr = wn * 32 + nt * 16 + li;
      bfrag[nt] = *(const short8*)&lbuf[nr * BSTRIDE + ks * 32 + quad * 8];
    }
#pragma unroll
    for (int mt = 0; mt < 2; ++mt)
#pragma unroll
      for (int nt = 0; nt < 2; ++nt)
        acc[mt][nt] = __builtin_amdgcn_mfma_f32_16x16x32_bf16(af[mt], bfrag[nt], acc[mt][nt], 0, 0, 0);
  }
  __syncthreads();                     // done reading lbuf as B
  unsigned short (*ct)[68] = (unsigned short(*)[68])lbuf;   // alias as C-tile
  const float qs = (wsel == 0) ? 0.15811388300841898f * 1.4426950408889634f : 1.0f;
#pragma unroll
  for (int mt = 0; mt < 2; ++mt)
#pragma unroll
    for (int nt = 0; nt < 2; ++nt)
#pragma unroll
      for (int r = 0; r < 4; ++r)
        ct[wm * 32 + mt * 16 + quad * 4 + r][wn * 32 + nt * 16 + li] =
            bfbits(acc[mt][nt][r] * qs);
  __syncthreads();
  int kt = m0 >> 6;
  if (wsel == 0) {                     // q row-major [h][tok][40]
    int row = threadIdx.x >> 2, c4 = threadIdx.x & 3;
    int grow = m0 + row;
    if (grow < N_TOK) {
#pragma unroll
      for (int i = 0; i < 4; ++i) {
        int cg = c4 + i * 4;           // 4-col chunk; 4|40 -> never crosses a head
        int col = n_in + cg * 4;
        int h = col / DH, d = col % DH;
        ushort4 pk = *(const ushort4*)&ct[row][cg * 4];
        *(ushort4*)(q + (long)h * N_TOK * DH + (long)grow * DH + d) = pk;
      }
    }
  } else if (wsel == 1) {              // K fragment layout (8-d runs never cross 64-col tile)
#pragma unroll
    for (int rep = 0; rep < 2; ++rep) {
      int u = threadIdx.x + rep * 256;
      int row = u >> 3, c8 = (u & 7) * 8;
      int gcol = n_in + c8;
      int h = gcol / DH, d0 = gcol % DH;          // d0 in {0,8,16,24,32}
      int li2 = row & 15, nt2 = row >> 4;
      long base = (((long)h * 65 + kt) * 4 + nt2) * 640 +
                  (d0 < 32 ? ((d0 >> 3) * 16 + li2) * 8 : 512 + li2 * 8);
      ushort4 a = *(const ushort4*)&ct[row][c8];
      ushort4 b = *(const ushort4*)&ct[row][c8 + 4];
      *(ushort4*)(kswz + base) = a;
      *(ushort4*)(kswz + base + 4) = b;
    }
  } else {                             // V fragment layout (8-tok octets, column gather)
#pragma unroll
    for (int rep = 0; rep < 2; ++rep) {
      int u = threadIdx.x + rep * 256;
      int g = u & 7, dcol = u >> 3;
      int gcol = n_in + dcol;
      int h = gcol / DH, d = gcol % DH;
      int dt = d >> 4, li2 = d & 15, ksv = g >> 2, q2 = g & 3;
      union { unsigned short e[8]; ushort4 v[2]; } o;
#pragma unroll
      for (int j = 0; j < 8; ++j) o.e[j] = ct[g * 8 + j][dcol];
      long base = (((long)h * 65 + kt) * 6 + ksv * 3 + dt) * 512 + (q2 * 16 + li2) * 8;
      *(ushort4*)(vswz + base) = o.v[0];
      *(ushort4*)(vswz + base + 4) = o.v[1];
    }
  }
}

// ---------- split-K flash attention: static-max softmax, 32 q-rows/wave,
// 4-wave blocks, SINGLE P buffer (17.4KB LDS) + min-6-waves/EU bound ----------
__global__ __launch_bounds__(256, 6) void attn_kernel(
    const bf16* __restrict__ qg, const bf16* __restrict__ kswz, const bf16* __restrict__ vswz,
    const unsigned short* __restrict__ awA, const unsigned short* __restrict__ bwB,
    float* __restrict__ opart, float* __restrict__ lpart) {
  __shared__ unsigned short pbuf[4][32][68];   // wave, row, col (single buffer)
  int bid = blockIdx.x;
  int h = bid & 7;
  int sp = (bid >> 3) & 3;
  int qt = bid >> 5;                   // 0..32 (128 q-rows per block)
  int kt0 = (sp * 65) >> 2;
  int kt1 = ((sp + 1) * 65) >> 2;
  int wv = threadIdx.x >> 6, lane = threadIdx.x & 63;
  int quad = lane >> 4, li = lane & 15;
  const bf16* qh = qg + h * (N_TOK * DH);
  const bf16* kz = kswz + (long)h * 65 * 2560;
  const bf16* vz = vswz + (long)h * 65 * 3072;

  int qrow_base = qt * 128 + wv * 32;  // up to 4223 < N_SP (awA/opart padded)
  short8 qa0[2], qa1[2];
  unsigned int aw[2][4]; int qi[2][4];
#pragma unroll
  for (int mt = 0; mt < 2; ++mt) {
    int qr = qrow_base + mt * 16 + li; if (qr > N_TOK - 1) qr = N_TOK - 1;
    qa0[mt] = *(const short8*)(qh + qr * DH + quad * 8);
    qa1[mt] = (quad == 0) ? *(const short8*)(qh + qr * DH + 32) : (short8)(__bf16)0.0f;
#pragma unroll
    for (int r = 0; r < 4; ++r) {
      qi[mt][r] = qrow_base + mt * 16 + quad * 4 + r;
      aw[mt][r] = awA[qi[mt][r]];      // padded rows -> 0 -> fully masked -> o=l=0
    }
  }

  f32x4 o[2][3];
#pragma unroll
  for (int mt = 0; mt < 2; ++mt)
#pragma unroll
    for (int d = 0; d < 3; ++d) o[mt][d] = (f32x4){0.f, 0.f, 0.f, 0.f};
  const f32x4 cm8 = (f32x4){-8.f, -8.f, -8.f, -8.f};   // static softmax shift
  int dkt = qrow_base >> 6;            // the single ktile containing this wave's diagonal

  for (int kt = kt0; kt < kt1; ++kt) {
    const bf16* kb_base = kz + (long)kt * 2560;
    f32x4 s[2][4];
    unsigned int bw[4];
#pragma unroll
    for (int nt = 0; nt < 4; ++nt) {
      bw[nt] = bwB[kt * 64 + nt * 16 + li];
      short8 kb0 = *(const short8*)(kb_base + nt * 640 + lane * 8);       // coalesced 1KB
      short8 kb1 = (quad == 0) ? *(const short8*)(kb_base + nt * 640 + 512 + li * 8)
                               : (short8)(__bf16)0.0f;
      s[0][nt] = __builtin_amdgcn_mfma_f32_16x16x32_bf16(qa0[0], kb0, cm8, 0, 0, 0);
      s[0][nt] = __builtin_amdgcn_mfma_f32_16x16x32_bf16(qa1[0], kb1, s[0][nt], 0, 0, 0);
      s[1][nt] = __builtin_amdgcn_mfma_f32_16x16x32_bf16(qa0[1], kb0, cm8, 0, 0, 0);
      s[1][nt] = __builtin_amdgcn_mfma_f32_16x16x32_bf16(qa1[1], kb1, s[1][nt], 0, 0, 0);
    }
    // V fragments (independent of P) issued before the exp phase
    short8 vb[2][3];
#pragma unroll
    for (int ksv = 0; ksv < 2; ++ksv)
#pragma unroll
      for (int dt = 0; dt < 3; ++dt)
        vb[ksv][dt] = *(const short8*)(vz + ((long)kt * 6 + ksv * 3 + dt) * 512 + lane * 8);
    // mask -> exp2 (native) -> truncation-pack bf16 -> LDS
    if (kt == dkt) {
#pragma unroll
      for (int mt = 0; mt < 2; ++mt)
#pragma unroll
        for (int nt = 0; nt < 4; ++nt)
#pragma unroll
          for (int r = 0; r < 4; ++r) {
            bool kp = ((aw[mt][r] & bw[nt]) != 0u) ||
                      (qi[mt][r] == (kt * 64 + nt * 16 + li));
            float p = EXP2F(kp ? s[mt][nt][r] : -1e5f);
            pbuf[wv][mt * 16 + quad * 4 + r][nt * 16 + li] =
                (unsigned short)(__builtin_bit_cast(unsigned int, p) >> 16);
          }
    } else {
#pragma unroll
      for (int mt = 0; mt < 2; ++mt)
#pragma unroll
        for (int nt = 0; nt < 4; ++nt)
#pragma unroll
          for (int r = 0; r < 4; ++r) {
            bool kp = (aw[mt][r] & bw[nt]) != 0u;
            float p = EXP2F(kp ? s[mt][nt][r] : -1e5f);
            pbuf[wv][mt * 16 + quad * 4 + r][nt * 16 + li] =
                (unsigned short)(__builtin_bit_cast(unsigned int, p) >> 16);
          }
    }
    // PV: P (A-layout, own wave's LDS region; compiler inserts lgkmcnt) x V fragments.
    // vswz dt=2 col d=40 is all-ones -> o[mt][2] lane li==8 accumulates l for free.
#pragma unroll
    for (int ksv = 0; ksv < 2; ++ksv) {
      union { short8 v; ushort4 u[2]; } fp[2];
#pragma unroll
      for (int mt = 0; mt < 2; ++mt) {
        fp[mt].u[0] = *(const ushort4*)&pbuf[wv][mt * 16 + li][ksv * 32 + quad * 8];
        fp[mt].u[1] = *(const ushort4*)&pbuf[wv][mt * 16 + li][ksv * 32 + quad * 8 + 4];
      }
#pragma unroll
      for (int dt = 0; dt < 3; ++dt) {
        o[0][dt] = __builtin_amdgcn_mfma_f32_16x16x32_bf16(fp[0].v, vb[ksv][dt], o[0][dt], 0, 0, 0);
        o[1][dt] = __builtin_amdgcn_mfma_f32_16x16x32_bf16(fp[1].v, vb[ksv][dt], o[1][dt], 0, 0, 0);
      }
    }
  }
  long pb2 = (long)(sp * 8 + h) * N_SP;
#pragma unroll
  for (int mt = 0; mt < 2; ++mt) {
#pragma unroll
    for (int dt = 0; dt < 3; ++dt) {
      int d = dt * 16 + li;
      if (d < DH) {
#pragma unroll
        for (int r = 0; r < 4; ++r)
          opart[(pb2 + qi[mt][r]) * DH + d] = o[mt][dt][r];
      }
    }
    if (li == 8) {
#pragma unroll
      for (int r = 0; r < 4; ++r) lpart[pb2 + qi[mt][r]] = o[mt][2][r];
    }
  }
}

// ---------- combine partials across splits (equal weights), float4-vectorized ----------
__global__ __launch_bounds__(256) void combine_kernel(
    const float* __restrict__ opart, const float* __restrict__ lpart,
    bf16* __restrict__ attn) {
  int id = blockIdx.x * 256 + threadIdx.x;   // (h, row, d4): 8*4128*10
  if (id >= 8 * N_TOK * 10) return;
  int d4 = id % 10;
  int rw = (id / 10) % N_TOK;
  int h = id / (10 * N_TOK);
  float4 osum = make_float4(0.f, 0.f, 0.f, 0.f);
  float lsum = 0.f;
#pragma unroll
  for (int s = 0; s < SPLITS; ++s) {
    long rb = (long)(s * 8 + h) * N_SP + rw;
    float4 ov = *(const float4*)(opart + rb * DH + d4 * 4);
    osum.x += ov.x; osum.y += ov.y; osum.z += ov.z; osum.w += ov.w;
    lsum += lpart[rb];
  }
  float rl = 1.0f / fmaxf(lsum, 1e-30f);
  union { short4 s4; unsigned short hh[4]; } u;
  u.hh[0] = bfbits(osum.x * rl); u.hh[1] = bfbits(osum.y * rl);
  u.hh[2] = bfbits(osum.z * rl); u.hh[3] = bfbits(osum.w * rl);
  *(short4*)(attn + rw * QD + h * DH + d4 * 4) = u.s4;
}

// ---------- output projection + bias (LDS-staged B from raw Wo, self-sniff) ----------
__global__ __launch_bounds__(256) void gemm_out(
    const bf16* __restrict__ A, const void* __restrict__ Wo,
    const void* __restrict__ bias, const void* __restrict__ att,
    void* __restrict__ out) {
  bool isbf = blk_sniff((const unsigned short*)att, 256);
  __shared__ unsigned short lbuf[64 * BSTRIDE];
  int m0 = blockIdx.x * 64;
  int n0 = blockIdx.y * 64;
  {
    int krow0 = threadIdx.x >> 2;
    int c16 = (threadIdx.x & 3) * 16;
#pragma unroll
    for (int it = 0; it < 5; ++it) {
      int kk = it * 64 + krow0;
      if (!isbf) {
        const float* wp = (const float*)Wo + (long)kk * QD + n0 + c16;
        float4 f0 = *(const float4*)wp,     f1 = *(const float4*)(wp + 4);
        float4 f2 = *(const float4*)(wp + 8), f3 = *(const float4*)(wp + 12);
        float fv[16] = {f0.x, f0.y, f0.z, f0.w, f1.x, f1.y, f1.z, f1.w,
                        f2.x, f2.y, f2.z, f2.w, f3.x, f3.y, f3.z, f3.w};
#pragma unroll
        for (int j = 0; j < 16; ++j) lbuf[(c16 + j) * BSTRIDE + kk] = bfbits(fv[j]);
      } else {
        const unsigned short* wp = (const unsigned short*)Wo + (long)kk * QD + n0 + c16;
#pragma unroll
        for (int j4 = 0; j4 < 4; ++j4) {
          ushort4 u4 = *(const ushort4*)(wp + j4 * 4);
          lbuf[(c16 + j4 * 4 + 0) * BSTRIDE + kk] = u4.x;
          lbuf[(c16 + j4 * 4 + 1) * BSTRIDE + kk] = u4.y;
          lbuf[(c16 + j4 * 4 + 2) * BSTRIDE + kk] = u4.z;
          lbuf[(c16 + j4 * 4 + 3) * BSTRIDE + kk] = u4.w;
        }
      }
    }
  }
  __syncthreads();
  int wv = threadIdx.x >> 6, lane = threadIdx.x & 63;
  int quad = lane >> 4, li = lane & 15;
  int wm = wv >> 1, wn = wv & 1;
  f32x4 acc[2][2];
#pragma unroll
  for (int a = 0; a < 2; a++)
#pragma unroll
    for (int b = 0; b < 2; b++) acc[a][b] = (f32x4){0.f, 0.f, 0.f, 0.f};
#pragma unroll
  for (int ks = 0; ks < 10; ++ks) {
    short8 af[2], bfrag[2];
#pragma unroll
    for (int mt = 0; mt < 2; ++mt) {
      int r = m0 + wm * 32 + mt * 16 + li;
      r = r < N_TOK ? r : N_TOK - 1;
      af[mt] = *(const short8*)(A + r * QD + ks * 32 + quad * 8);
    }
#pragma unroll
    for (int nt = 0; nt < 2; ++nt) {
      int nr = wn * 32 + nt * 16 + li;
      bfrag[nt] = *(const short8*)&lbuf[nr * BSTRIDE + ks * 32 + quad * 8];
    }
#pragma unroll
    for (int mt = 0; mt < 2; ++mt)
#pragma unroll
      for (int nt = 0; nt < 2; ++nt)
        acc[mt][nt] = __builtin_amdgcn_mfma_f32_16x16x32_bf16(af[mt], bfrag[nt], acc[mt][nt], 0, 0, 0);
  }
#pragma unroll
  for (int mt = 0; mt < 2; ++mt)
#pragma unroll
    for (int nt = 0; nt < 2; ++nt)
#pragma unroll
      for (int r = 0; r < 4; ++r) {
        int row = m0 + wm * 32 + mt * 16 + quad * 4 + r;
        if (row >= N_TOK) continue;
        int col = n0 + wn * 32 + nt * 16 + li;
        float val = acc[mt][nt][r] + loadS(bias, col, isbf);
        if (isbf) ((bf16*)out)[row * QD + col] = (bf16)val;
        else      ((float*)out)[row * QD + col] = val;
      }
}

extern "C" void kernel_launch(void* const* d_in, const int* in_sizes, int n_in,
                              void* d_out, int out_size, void* d_ws, size_t ws_size,
                              hipStream_t stream) {
  (void)in_sizes; (void)n_in; (void)out_size; (void)ws_size;
  const void* x   = d_in[0];
  const void* att = d_in[1];
  const void* Wq  = d_in[2];
  const void* Wk  = d_in[3];
  const void* Wv  = d_in[4];
  const void* Wo  = d_in[5];
  const void* bo  = d_in[6];
  char* ws = (char*)d_ws;
  unsigned short* awA = (unsigned short*)(ws + 0);        // 8448
  unsigned short* bwB = (unsigned short*)(ws + 8704);     // 8448
  bf16* qb    = (bf16*)(ws + 17408);                      // 2641920
  bf16* kswz  = (bf16*)(ws + 2659328);                    // 2662400
  bf16* vswz  = (bf16*)(ws + 5321728);                    // 3194880
  bf16* attnb = (bf16*)(ws + 8516608);                    // 2641920
  float* opart = (float*)(ws + 11158528);                 // 21626880
  float* lpart = (float*)(ws + 32785408);                 // 540672 -> total 33326080

  dim3 g1(65, 16);   // by 0..14 = GEMM tiles, by 15 = masks + vswz ones
  qkv_mega<<<g1, 256, 0, stream>>>(x, att, Wq, Wk, Wv, qb, kswz, vswz, awA, bwB);
  attn_kernel<<<33 * SPLITS * 8, 256, 0, stream>>>(qb, kswz, vswz, awA, bwB, opart, lpart);
  combine_kernel<<<(8 * N_TOK * 10 + 255) / 256, 256, 0, stream>>>(opart, lpart, attnb);
  dim3 g2(65, 5);
  gemm_out<<<g2, 256, 0, stream>>>(attnb, Wo, bo, att, d_out);
}

// Round 13
// 182.483 us; speedup vs baseline: 3.1541x; 3.1541x over previous
//
#include <hip/hip_runtime.h>

typedef __bf16 bf16;
using short8 = __attribute__((ext_vector_type(8))) __bf16;
using f32x4  = __attribute__((ext_vector_type(4))) float;

#define N_TOK 4128
#define QD    320
#define DH    40
#define W_VIS 4096
#define SPLITS 4
#define N_SP  4224
#define BSTRIDE 344   /* LDS B-stage stride: 16B-aligned rows, 2-way (free) frag reads */

#if __has_builtin(__builtin_amdgcn_exp2f)
#define EXP2F(x) __builtin_amdgcn_exp2f(x)
#else
#define EXP2F(x) exp2f(x)
#endif

__device__ __forceinline__ float loadS(const void* b, long i, bool isbf) {
  return isbf ? (float)((const bf16*)b)[i] : ((const float*)b)[i];
}
__device__ __forceinline__ unsigned short bfbits(float x) {
  bf16 h = (bf16)x;
  return __builtin_bit_cast(unsigned short, h);
}

// per-block dtype sniff: att is {0,1}; as fp32 its even halfwords are all 0;
// as bf16 ~15% are 0x3F80. 256 samples -> P(miss) ~ 0.85^256 ~ 4e-19.
__device__ __forceinline__ bool blk_sniff(const unsigned short* att_h, int nthr) {
  __shared__ int s;
  if (threadIdx.x == 0) s = 0;
  __syncthreads();
  int step = 8192 / nthr;
  if (att_h[threadIdx.x * step] != 0) atomicOr(&s, 1);
  __syncthreads();
  return s != 0;
}

// dtype-aware A-fragment (8 contiguous k at row) -> bf16 bits
__device__ __forceinline__ short8 load_afrag(const void* x, long row, int koff, bool isbf) {
  if (isbf) return *(const short8*)((const bf16*)x + row * QD + koff);
  const float* f = (const float*)x + row * QD + koff;
  float4 a = *(const float4*)f, b = *(const float4*)(f + 4);
  union { short8 v; unsigned short e[8]; } u;
  u.e[0] = bfbits(a.x); u.e[1] = bfbits(a.y); u.e[2] = bfbits(a.z); u.e[3] = bfbits(a.w);
  u.e[4] = bfbits(b.x); u.e[5] = bfbits(b.y); u.e[6] = bfbits(b.z); u.e[7] = bfbits(b.w);
  return u.v;
}

// ---------- mega QKV: masks+ones (by==15) | GEMM with LDS-staged B from raw W,
// epilogue writes q row-major + kswz/vswz fragment layouts straight from LDS C ----------
__global__ __launch_bounds__(256) void qkv_mega(
    const void* __restrict__ x, const void* __restrict__ att,
    const void* __restrict__ Wq, const void* __restrict__ Wk, const void* __restrict__ Wv,
    bf16* __restrict__ q, bf16* __restrict__ kswz, bf16* __restrict__ vswz,
    unsigned short* __restrict__ awA, unsigned short* __restrict__ bwB) {
  bool isbf = blk_sniff((const unsigned short*)att, 256);
  if (blockIdx.y == 15) {      // ---- util slice: mask words + vswz d=40..47 ones/zeros
    int flat = blockIdx.x * 256 + threadIdx.x;
    if (flat < N_SP) {
      int t = flat;
      unsigned int Aw = 0u, Bw = 0u;
      if (t < N_TOK) {
        unsigned int b9 = 0u; bool forced = false;
        if (t < W_VIS) {
#pragma unroll
          for (int o = 0; o < 8; ++o)
            if (loadS(att, o * W_VIS + t, isbf) != 0.0f) b9 |= (1u << o);
        } else {
          int g = t - W_VIS;
          int rep = g >> 3, oo = g & 7;
          forced = (rep == 1 || rep == 2);
          b9 = 0x100u | (forced ? 0u : (1u << oo));
        }
        Aw = b9 | (forced ? 0x200u : 0u) | 0x400u;
        Bw = b9 | (forced ? 0x400u : 0u) | 0x200u;
      }
      awA[t] = (unsigned short)Aw;
      bwB[t] = (unsigned short)Bw;
    } else if (flat - N_SP < 8320) {
      int idx = flat - N_SP;
#pragma unroll
      for (int m = 0; m < 4; ++m) {
        int t = idx * 4 + m;           // 0..33279
        int li8 = t & 7; int t2 = t >> 3;
        int q2 = t2 & 3; t2 >>= 2;
        int ksv = t2 & 1; t2 >>= 1;
        int kt = t2 % 65, h = t2 / 65;
        bf16 val = (li8 == 0) ? (bf16)1.0f : (bf16)0.0f;   // d=40 ones (l via MFMA)
        short8 v8 = {val, val, val, val, val, val, val, val};
        long base = (((long)h * 65 + kt) * 6 + ksv * 3 + 2) * 512;
        *(short8*)(vswz + base + (q2 * 16 + 8 + li8) * 8) = v8;
      }
    }
    return;
  }
  __shared__ unsigned short lbuf[64 * BSTRIDE];   // B-stage; aliased as C-tile later
  int m0 = blockIdx.x * 64;
  int ng = blockIdx.y * 64;
  int wsel = ng / 320;                 // 0=q 1=k 2=v
  int n_in = ng % 320;
  const void* W = wsel == 0 ? Wq : wsel == 1 ? Wk : Wv;
  // ---- stage B: W[k][n] -> lbuf[n_rel][k] bf16 (coalesced global reads)
  {
    int krow0 = threadIdx.x >> 2;
    int c16 = (threadIdx.x & 3) * 16;
#pragma unroll
    for (int it = 0; it < 5; ++it) {
      int kk = it * 64 + krow0;
      if (!isbf) {
        const float* wp = (const float*)W + (long)kk * QD + n_in + c16;
        float4 f0 = *(const float4*)wp,     f1 = *(const float4*)(wp + 4);
        float4 f2 = *(const float4*)(wp + 8), f3 = *(const float4*)(wp + 12);
        float fv[16] = {f0.x, f0.y, f0.z, f0.w, f1.x, f1.y, f1.z, f1.w,
                        f2.x, f2.y, f2.z, f2.w, f3.x, f3.y, f3.z, f3.w};
#pragma unroll
        for (int j = 0; j < 16; ++j) lbuf[(c16 + j) * BSTRIDE + kk] = bfbits(fv[j]);
      } else {
        const unsigned short* wp = (const unsigned short*)W + (long)kk * QD + n_in + c16;
#pragma unroll
        for (int j4 = 0; j4 < 4; ++j4) {
          ushort4 u4 = *(const ushort4*)(wp + j4 * 4);
          lbuf[(c16 + j4 * 4 + 0) * BSTRIDE + kk] = u4.x;
          lbuf[(c16 + j4 * 4 + 1) * BSTRIDE + kk] = u4.y;
          lbuf[(c16 + j4 * 4 + 2) * BSTRIDE + kk] = u4.z;
          lbuf[(c16 + j4 * 4 + 3) * BSTRIDE + kk] = u4.w;
        }
      }
    }
  }
  __syncthreads();
  int wv = threadIdx.x >> 6, lane = threadIdx.x & 63;
  int quad = lane >> 4, li = lane & 15;
  int wm = wv >> 1, wn = wv & 1;
  f32x4 acc[2][2];
#pragma unroll
  for (int a = 0; a < 2; a++)
#pragma unroll
    for (int b = 0; b < 2; b++) acc[a][b] = (f32x4){0.f, 0.f, 0.f, 0.f};
#pragma unroll
  for (int ks = 0; ks < 10; ++ks) {
    short8 af[2], bfrag[2];
#pragma unroll
    for (int mt = 0; mt < 2; ++mt) {
      long r = m0 + wm * 32 + mt * 16 + li;
      if (r > N_TOK - 1) r = N_TOK - 1;
      af[mt] = load_afrag(x, r, ks * 32 + quad * 8, isbf);
    }
#pragma unroll
    for (int nt = 0; nt < 2; ++nt) {
      int nr = wn * 32 + nt * 16 + li;
      bfrag[nt] = *(const short8*)&lbuf[nr * BSTRIDE + ks * 32 + quad * 8];
    }
#pragma unroll
    for (int mt = 0; mt < 2; ++mt)
#pragma unroll
      for (int nt = 0; nt < 2; ++nt)
        acc[mt][nt] = __builtin_amdgcn_mfma_f32_16x16x32_bf16(af[mt], bfrag[nt], acc[mt][nt], 0, 0, 0);
  }
  __syncthreads();                     // done reading lbuf as B
  unsigned short (*ct)[68] = (unsigned short(*)[68])lbuf;   // alias as C-tile
  const float qs = (wsel == 0) ? 0.15811388300841898f * 1.4426950408889634f : 1.0f;
#pragma unroll
  for (int mt = 0; mt < 2; ++mt)
#pragma unroll
    for (int nt = 0; nt < 2; ++nt)
#pragma unroll
      for (int r = 0; r < 4; ++r)
        ct[wm * 32 + mt * 16 + quad * 4 + r][wn * 32 + nt * 16 + li] =
            bfbits(acc[mt][nt][r] * qs);
  __syncthreads();
  int kt = m0 >> 6;
  if (wsel == 0) {                     // q row-major [h][tok][40]
    int row = threadIdx.x >> 2, c4 = threadIdx.x & 3;
    int grow = m0 + row;
    if (grow < N_TOK) {
#pragma unroll
      for (int i = 0; i < 4; ++i) {
        int cg = c4 + i * 4;           // 4-col chunk; 4|40 -> never crosses a head
        int col = n_in + cg * 4;
        int h = col / DH, d = col % DH;
        ushort4 pk = *(const ushort4*)&ct[row][cg * 4];
        *(ushort4*)(q + (long)h * N_TOK * DH + (long)grow * DH + d) = pk;
      }
    }
  } else if (wsel == 1) {              // K fragment layout (8-d runs never cross 64-col tile)
#pragma unroll
    for (int rep = 0; rep < 2; ++rep) {
      int u = threadIdx.x + rep * 256;
      int row = u >> 3, c8 = (u & 7) * 8;
      int gcol = n_in + c8;
      int h = gcol / DH, d0 = gcol % DH;          // d0 in {0,8,16,24,32}
      int li2 = row & 15, nt2 = row >> 4;
      long base = (((long)h * 65 + kt) * 4 + nt2) * 640 +
                  (d0 < 32 ? ((d0 >> 3) * 16 + li2) * 8 : 512 + li2 * 8);
      ushort4 a = *(const ushort4*)&ct[row][c8];
      ushort4 b = *(const ushort4*)&ct[row][c8 + 4];
      *(ushort4*)(kswz + base) = a;
      *(ushort4*)(kswz + base + 4) = b;
    }
  } else {                             // V fragment layout (8-tok octets, column gather)
#pragma unroll
    for (int rep = 0; rep < 2; ++rep) {
      int u = threadIdx.x + rep * 256;
      int g = u & 7, dcol = u >> 3;
      int gcol = n_in + dcol;
      int h = gcol / DH, d = gcol % DH;
      int dt = d >> 4, li2 = d & 15, ksv = g >> 2, q2 = g & 3;
      union { unsigned short e[8]; ushort4 v[2]; } o;
#pragma unroll
      for (int j = 0; j < 8; ++j) o.e[j] = ct[g * 8 + j][dcol];
      long base = (((long)h * 65 + kt) * 6 + ksv * 3 + dt) * 512 + (q2 * 16 + li2) * 8;
      *(ushort4*)(vswz + base) = o.v[0];
      *(ushort4*)(vswz + base + 4) = o.v[1];
    }
  }
}

// ---------- split-K flash attention: static-max softmax, 32 q-rows/wave,
// 4-wave blocks, SINGLE P buffer (17.4KB LDS), safe (256,3) bound ----------
__global__ __launch_bounds__(256, 3) void attn_kernel(
    const bf16* __restrict__ qg, const bf16* __restrict__ kswz, const bf16* __restrict__ vswz,
    const unsigned short* __restrict__ awA, const unsigned short* __restrict__ bwB,
    float* __restrict__ opart, float* __restrict__ lpart) {
  __shared__ unsigned short pbuf[4][32][68];   // wave, row, col (single buffer)
  int bid = blockIdx.x;
  int h = bid & 7;
  int sp = (bid >> 3) & 3;
  int qt = bid >> 5;                   // 0..32 (128 q-rows per block)
  int kt0 = (sp * 65) >> 2;
  int kt1 = ((sp + 1) * 65) >> 2;
  int wv = threadIdx.x >> 6, lane = threadIdx.x & 63;
  int quad = lane >> 4, li = lane & 15;
  const bf16* qh = qg + h * (N_TOK * DH);
  const bf16* kz = kswz + (long)h * 65 * 2560;
  const bf16* vz = vswz + (long)h * 65 * 3072;

  int qrow_base = qt * 128 + wv * 32;  // up to 4223 < N_SP (awA/opart padded)
  short8 qa0[2], qa1[2];
  unsigned int aw[2][4]; int qi[2][4];
#pragma unroll
  for (int mt = 0; mt < 2; ++mt) {
    int qr = qrow_base + mt * 16 + li; if (qr > N_TOK - 1) qr = N_TOK - 1;
    qa0[mt] = *(const short8*)(qh + qr * DH + quad * 8);
    qa1[mt] = (quad == 0) ? *(const short8*)(qh + qr * DH + 32) : (short8)(__bf16)0.0f;
#pragma unroll
    for (int r = 0; r < 4; ++r) {
      qi[mt][r] = qrow_base + mt * 16 + quad * 4 + r;
      aw[mt][r] = awA[qi[mt][r]];      // padded rows -> 0 -> fully masked -> o=l=0
    }
  }

  f32x4 o[2][3];
#pragma unroll
  for (int mt = 0; mt < 2; ++mt)
#pragma unroll
    for (int d = 0; d < 3; ++d) o[mt][d] = (f32x4){0.f, 0.f, 0.f, 0.f};
  const f32x4 cm8 = (f32x4){-8.f, -8.f, -8.f, -8.f};   // static softmax shift
  int dkt = qrow_base >> 6;            // the single ktile containing this wave's diagonal

  for (int kt = kt0; kt < kt1; ++kt) {
    const bf16* kb_base = kz + (long)kt * 2560;
    f32x4 s[2][4];
    unsigned int bw[4];
#pragma unroll
    for (int nt = 0; nt < 4; ++nt) {
      bw[nt] = bwB[kt * 64 + nt * 16 + li];
      short8 kb0 = *(const short8*)(kb_base + nt * 640 + lane * 8);       // coalesced 1KB
      short8 kb1 = (quad == 0) ? *(const short8*)(kb_base + nt * 640 + 512 + li * 8)
                               : (short8)(__bf16)0.0f;
      s[0][nt] = __builtin_amdgcn_mfma_f32_16x16x32_bf16(qa0[0], kb0, cm8, 0, 0, 0);
      s[0][nt] = __builtin_amdgcn_mfma_f32_16x16x32_bf16(qa1[0], kb1, s[0][nt], 0, 0, 0);
      s[1][nt] = __builtin_amdgcn_mfma_f32_16x16x32_bf16(qa0[1], kb0, cm8, 0, 0, 0);
      s[1][nt] = __builtin_amdgcn_mfma_f32_16x16x32_bf16(qa1[1], kb1, s[1][nt], 0, 0, 0);
    }
    // V fragments (independent of P) issued before the exp phase
    short8 vb[2][3];
#pragma unroll
    for (int ksv = 0; ksv < 2; ++ksv)
#pragma unroll
      for (int dt = 0; dt < 3; ++dt)
        vb[ksv][dt] = *(const short8*)(vz + ((long)kt * 6 + ksv * 3 + dt) * 512 + lane * 8);
    // mask -> exp2 (native) -> truncation-pack bf16 -> LDS
    if (kt == dkt) {
#pragma unroll
      for (int mt = 0; mt < 2; ++mt)
#pragma unroll
        for (int nt = 0; nt < 4; ++nt)
#pragma unroll
          for (int r = 0; r < 4; ++r) {
            bool kp = ((aw[mt][r] & bw[nt]) != 0u) ||
                      (qi[mt][r] == (kt * 64 + nt * 16 + li));
            float p = EXP2F(kp ? s[mt][nt][r] : -1e5f);
            pbuf[wv][mt * 16 + quad * 4 + r][nt * 16 + li] =
                (unsigned short)(__builtin_bit_cast(unsigned int, p) >> 16);
          }
    } else {
#pragma unroll
      for (int mt = 0; mt < 2; ++mt)
#pragma unroll
        for (int nt = 0; nt < 4; ++nt)
#pragma unroll
          for (int r = 0; r < 4; ++r) {
            bool kp = (aw[mt][r] & bw[nt]) != 0u;
            float p = EXP2F(kp ? s[mt][nt][r] : -1e5f);
            pbuf[wv][mt * 16 + quad * 4 + r][nt * 16 + li] =
                (unsigned short)(__builtin_bit_cast(unsigned int, p) >> 16);
          }
    }
    // PV: P (A-layout, own wave's LDS region; compiler inserts lgkmcnt) x V fragments.
    // vswz dt=2 col d=40 is all-ones -> o[mt][2] lane li==8 accumulates l for free.
#pragma unroll
    for (int ksv = 0; ksv < 2; ++ksv) {
      union { short8 v; ushort4 u[2]; } fp[2];
#pragma unroll
      for (int mt = 0; mt < 2; ++mt) {
        fp[mt].u[0] = *(const ushort4*)&pbuf[wv][mt * 16 + li][ksv * 32 + quad * 8];
        fp[mt].u[1] = *(const ushort4*)&pbuf[wv][mt * 16 + li][ksv * 32 + quad * 8 + 4];
      }
#pragma unroll
      for (int dt = 0; dt < 3; ++dt) {
        o[0][dt] = __builtin_amdgcn_mfma_f32_16x16x32_bf16(fp[0].v, vb[ksv][dt], o[0][dt], 0, 0, 0);
        o[1][dt] = __builtin_amdgcn_mfma_f32_16x16x32_bf16(fp[1].v, vb[ksv][dt], o[1][dt], 0, 0, 0);
      }
    }
  }
  long pb2 = (long)(sp * 8 + h) * N_SP;
#pragma unroll
  for (int mt = 0; mt < 2; ++mt) {
#pragma unroll
    for (int dt = 0; dt < 3; ++dt) {
      int d = dt * 16 + li;
      if (d < DH) {
#pragma unroll
        for (int r = 0; r < 4; ++r)
          opart[(pb2 + qi[mt][r]) * DH + d] = o[mt][dt][r];
      }
    }
    if (li == 8) {
#pragma unroll
      for (int r = 0; r < 4; ++r) lpart[pb2 + qi[mt][r]] = o[mt][2][r];
    }
  }
}

// ---------- combine partials across splits (equal weights), float4-vectorized ----------
__global__ __launch_bounds__(256) void combine_kernel(
    const float* __restrict__ opart, const float* __restrict__ lpart,
    bf16* __restrict__ attn) {
  int id = blockIdx.x * 256 + threadIdx.x;   // (h, row, d4): 8*4128*10
  if (id >= 8 * N_TOK * 10) return;
  int d4 = id % 10;
  int rw = (id / 10) % N_TOK;
  int h = id / (10 * N_TOK);
  float4 osum = make_float4(0.f, 0.f, 0.f, 0.f);
  float lsum = 0.f;
#pragma unroll
  for (int s = 0; s < SPLITS; ++s) {
    long rb = (long)(s * 8 + h) * N_SP + rw;
    float4 ov = *(const float4*)(opart + rb * DH + d4 * 4);
    osum.x += ov.x; osum.y += ov.y; osum.z += ov.z; osum.w += ov.w;
    lsum += lpart[rb];
  }
  float rl = 1.0f / fmaxf(lsum, 1e-30f);
  union { short4 s4; unsigned short hh[4]; } u;
  u.hh[0] = bfbits(osum.x * rl); u.hh[1] = bfbits(osum.y * rl);
  u.hh[2] = bfbits(osum.z * rl); u.hh[3] = bfbits(osum.w * rl);
  *(short4*)(attn + rw * QD + h * DH + d4 * 4) = u.s4;
}

// ---------- output projection + bias (LDS-staged B from raw Wo, self-sniff) ----------
__global__ __launch_bounds__(256) void gemm_out(
    const bf16* __restrict__ A, const void* __restrict__ Wo,
    const void* __restrict__ bias, const void* __restrict__ att,
    void* __restrict__ out) {
  bool isbf = blk_sniff((const unsigned short*)att, 256);
  __shared__ unsigned short lbuf[64 * BSTRIDE];
  int m0 = blockIdx.x * 64;
  int n0 = blockIdx.y * 64;
  {
    int krow0 = threadIdx.x >> 2;
    int c16 = (threadIdx.x & 3) * 16;
#pragma unroll
    for (int it = 0; it < 5; ++it) {
      int kk = it * 64 + krow0;
      if (!isbf) {
        const float* wp = (const float*)Wo + (long)kk * QD + n0 + c16;
        float4 f0 = *(const float4*)wp,     f1 = *(const float4*)(wp + 4);
        float4 f2 = *(const float4*)(wp + 8), f3 = *(const float4*)(wp + 12);
        float fv[16] = {f0.x, f0.y, f0.z, f0.w, f1.x, f1.y, f1.z, f1.w,
                        f2.x, f2.y, f2.z, f2.w, f3.x, f3.y, f3.z, f3.w};
#pragma unroll
        for (int j = 0; j < 16; ++j) lbuf[(c16 + j) * BSTRIDE + kk] = bfbits(fv[j]);
      } else {
        const unsigned short* wp = (const unsigned short*)Wo + (long)kk * QD + n0 + c16;
#pragma unroll
        for (int j4 = 0; j4 < 4; ++j4) {
          ushort4 u4 = *(const ushort4*)(wp + j4 * 4);
          lbuf[(c16 + j4 * 4 + 0) * BSTRIDE + kk] = u4.x;
          lbuf[(c16 + j4 * 4 + 1) * BSTRIDE + kk] = u4.y;
          lbuf[(c16 + j4 * 4 + 2) * BSTRIDE + kk] = u4.z;
          lbuf[(c16 + j4 * 4 + 3) * BSTRIDE + kk] = u4.w;
        }
      }
    }
  }
  __syncthreads();
  int wv = threadIdx.x >> 6, lane = threadIdx.x & 63;
  int quad = lane >> 4, li = lane & 15;
  int wm = wv >> 1, wn = wv & 1;
  f32x4 acc[2][2];
#pragma unroll
  for (int a = 0; a < 2; a++)
#pragma unroll
    for (int b = 0; b < 2; b++) acc[a][b] = (f32x4){0.f, 0.f, 0.f, 0.f};
#pragma unroll
  for (int ks = 0; ks < 10; ++ks) {
    short8 af[2], bfrag[2];
#pragma unroll
    for (int mt = 0; mt < 2; ++mt) {
      int r = m0 + wm * 32 + mt * 16 + li;
      r = r < N_TOK ? r : N_TOK - 1;
      af[mt] = *(const short8*)(A + r * QD + ks * 32 + quad * 8);
    }
#pragma unroll
    for (int nt = 0; nt < 2; ++nt) {
      int nr = wn * 32 + nt * 16 + li;
      bfrag[nt] = *(const short8*)&lbuf[nr * BSTRIDE + ks * 32 + quad * 8];
    }
#pragma unroll
    for (int mt = 0; mt < 2; ++mt)
#pragma unroll
      for (int nt = 0; nt < 2; ++nt)
        acc[mt][nt] = __builtin_amdgcn_mfma_f32_16x16x32_bf16(af[mt], bfrag[nt], acc[mt][nt], 0, 0, 0);
  }
#pragma unroll
  for (int mt = 0; mt < 2; ++mt)
#pragma unroll
    for (int nt = 0; nt < 2; ++nt)
#pragma unroll
      for (int r = 0; r < 4; ++r) {
        int row = m0 + wm * 32 + mt * 16 + quad * 4 + r;
        if (row >= N_TOK) continue;
        int col = n0 + wn * 32 + nt * 16 + li;
        float val = acc[mt][nt][r] + loadS(bias, col, isbf);
        if (isbf) ((bf16*)out)[row * QD + col] = (bf16)val;
        else      ((float*)out)[row * QD + col] = val;
      }
}

extern "C" void kernel_launch(void* const* d_in, const int* in_sizes, int n_in,
                              void* d_out, int out_size, void* d_ws, size_t ws_size,
                              hipStream_t stream) {
  (void)in_sizes; (void)n_in; (void)out_size; (void)ws_size;
  const void* x   = d_in[0];
  const void* att = d_in[1];
  const void* Wq  = d_in[2];
  const void* Wk  = d_in[3];
  const void* Wv  = d_in[4];
  const void* Wo  = d_in[5];
  const void* bo  = d_in[6];
  char* ws = (char*)d_ws;
  unsigned short* awA = (unsigned short*)(ws + 0);        // 8448
  unsigned short* bwB = (unsigned short*)(ws + 8704);     // 8448
  bf16* qb    = (bf16*)(ws + 17408);                      // 2641920
  bf16* kswz  = (bf16*)(ws + 2659328);                    // 2662400
  bf16* vswz  = (bf16*)(ws + 5321728);                    // 3194880
  bf16* attnb = (bf16*)(ws + 8516608);                    // 2641920
  float* opart = (float*)(ws + 11158528);                 // 21626880
  float* lpart = (float*)(ws + 32785408);                 // 540672 -> total 33326080

  dim3 g1(65, 16);   // by 0..14 = GEMM tiles, by 15 = masks + vswz ones
  qkv_mega<<<g1, 256, 0, stream>>>(x, att, Wq, Wk, Wv, qb, kswz, vswz, awA, bwB);
  attn_kernel<<<33 * SPLITS * 8, 256, 0, stream>>>(qb, kswz, vswz, awA, bwB, opart, lpart);
  combine_kernel<<<(8 * N_TOK * 10 + 255) / 256, 256, 0, stream>>>(opart, lpart, attnb);
  dim3 g2(65, 5);
  gemm_out<<<g2, 256, 0, stream>>>(attnb, Wo, bo, att, d_out);
}

// Round 14
// 175.647 us; speedup vs baseline: 3.2769x; 1.0389x over previous
//
#include <hip/hip_runtime.h>

typedef __bf16 bf16;
using short8 = __attribute__((ext_vector_type(8))) __bf16;
using f32x4  = __attribute__((ext_vector_type(4))) float;

#define N_TOK 4128
#define QD    320
#define DH    40
#define W_VIS 4096
#define SPLITS 8
#define N_SP  4224
#define BSTRIDE 344   /* LDS B-stage stride: 16B-aligned rows, 2-way (free) frag reads */

#if __has_builtin(__builtin_amdgcn_exp2f)
#define EXP2F(x) __builtin_amdgcn_exp2f(x)
#else
#define EXP2F(x) exp2f(x)
#endif

__device__ __forceinline__ float loadS(const void* b, long i, bool isbf) {
  return isbf ? (float)((const bf16*)b)[i] : ((const float*)b)[i];
}
__device__ __forceinline__ unsigned short bfbits(float x) {
  bf16 h = (bf16)x;
  return __builtin_bit_cast(unsigned short, h);
}

// per-block dtype sniff: att is {0,1}; as fp32 its even halfwords are all 0;
// as bf16 ~15% are 0x3F80. 256 samples -> P(miss) ~ 0.85^256 ~ 4e-19.
__device__ __forceinline__ bool blk_sniff(const unsigned short* att_h, int nthr) {
  __shared__ int s;
  if (threadIdx.x == 0) s = 0;
  __syncthreads();
  int step = 8192 / nthr;
  if (att_h[threadIdx.x * step] != 0) atomicOr(&s, 1);
  __syncthreads();
  return s != 0;
}

// dtype-aware A-fragment (8 contiguous k at row) -> bf16 bits
__device__ __forceinline__ short8 load_afrag(const void* x, long row, int koff, bool isbf) {
  if (isbf) return *(const short8*)((const bf16*)x + row * QD + koff);
  const float* f = (const float*)x + row * QD + koff;
  float4 a = *(const float4*)f, b = *(const float4*)(f + 4);
  union { short8 v; unsigned short e[8]; } u;
  u.e[0] = bfbits(a.x); u.e[1] = bfbits(a.y); u.e[2] = bfbits(a.z); u.e[3] = bfbits(a.w);
  u.e[4] = bfbits(b.x); u.e[5] = bfbits(b.y); u.e[6] = bfbits(b.z); u.e[7] = bfbits(b.w);
  return u.v;
}

// ---------- mega QKV: masks+ones (by==15) | GEMM with LDS-staged B from raw W,
// epilogue writes q row-major + kswz/vswz fragment layouts straight from LDS C ----------
__global__ __launch_bounds__(256) void qkv_mega(
    const void* __restrict__ x, const void* __restrict__ att,
    const void* __restrict__ Wq, const void* __restrict__ Wk, const void* __restrict__ Wv,
    bf16* __restrict__ q, bf16* __restrict__ kswz, bf16* __restrict__ vswz,
    unsigned short* __restrict__ awA, unsigned short* __restrict__ bwB) {
  bool isbf = blk_sniff((const unsigned short*)att, 256);
  if (blockIdx.y == 15) {      // ---- util slice: mask words + vswz d=40..47 ones/zeros
    int flat = blockIdx.x * 256 + threadIdx.x;
    if (flat < N_SP) {
      int t = flat;
      unsigned int Aw = 0u, Bw = 0u;
      if (t < N_TOK) {
        unsigned int b9 = 0u; bool forced = false;
        if (t < W_VIS) {
#pragma unroll
          for (int o = 0; o < 8; ++o)
            if (loadS(att, o * W_VIS + t, isbf) != 0.0f) b9 |= (1u << o);
        } else {
          int g = t - W_VIS;
          int rep = g >> 3, oo = g & 7;
          forced = (rep == 1 || rep == 2);
          b9 = 0x100u | (forced ? 0u : (1u << oo));
        }
        Aw = b9 | (forced ? 0x200u : 0u) | 0x400u;
        Bw = b9 | (forced ? 0x400u : 0u) | 0x200u;
      }
      awA[t] = (unsigned short)Aw;
      bwB[t] = (unsigned short)Bw;
    } else if (flat - N_SP < 8320) {
      int idx = flat - N_SP;
#pragma unroll
      for (int m = 0; m < 4; ++m) {
        int t = idx * 4 + m;           // 0..33279
        int li8 = t & 7; int t2 = t >> 3;
        int q2 = t2 & 3; t2 >>= 2;
        int ksv = t2 & 1; t2 >>= 1;
        int kt = t2 % 65, h = t2 / 65;
        bf16 val = (li8 == 0) ? (bf16)1.0f : (bf16)0.0f;   // d=40 ones (l via MFMA)
        short8 v8 = {val, val, val, val, val, val, val, val};
        long base = (((long)h * 65 + kt) * 6 + ksv * 3 + 2) * 512;
        *(short8*)(vswz + base + (q2 * 16 + 8 + li8) * 8) = v8;
      }
    }
    return;
  }
  __shared__ unsigned short lbuf[64 * BSTRIDE];   // B-stage; aliased as C-tile later
  int m0 = blockIdx.x * 64;
  int ng = blockIdx.y * 64;
  int wsel = ng / 320;                 // 0=q 1=k 2=v
  int n_in = ng % 320;
  const void* W = wsel == 0 ? Wq : wsel == 1 ? Wk : Wv;
  // ---- stage B: W[k][n] -> lbuf[n_rel][k] bf16 (coalesced global reads)
  {
    int krow0 = threadIdx.x >> 2;
    int c16 = (threadIdx.x & 3) * 16;
#pragma unroll
    for (int it = 0; it < 5; ++it) {
      int kk = it * 64 + krow0;
      if (!isbf) {
        const float* wp = (const float*)W + (long)kk * QD + n_in + c16;
        float4 f0 = *(const float4*)wp,     f1 = *(const float4*)(wp + 4);
        float4 f2 = *(const float4*)(wp + 8), f3 = *(const float4*)(wp + 12);
        float fv[16] = {f0.x, f0.y, f0.z, f0.w, f1.x, f1.y, f1.z, f1.w,
                        f2.x, f2.y, f2.z, f2.w, f3.x, f3.y, f3.z, f3.w};
#pragma unroll
        for (int j = 0; j < 16; ++j) lbuf[(c16 + j) * BSTRIDE + kk] = bfbits(fv[j]);
      } else {
        const unsigned short* wp = (const unsigned short*)W + (long)kk * QD + n_in + c16;
#pragma unroll
        for (int j4 = 0; j4 < 4; ++j4) {
          ushort4 u4 = *(const ushort4*)(wp + j4 * 4);
          lbuf[(c16 + j4 * 4 + 0) * BSTRIDE + kk] = u4.x;
          lbuf[(c16 + j4 * 4 + 1) * BSTRIDE + kk] = u4.y;
          lbuf[(c16 + j4 * 4 + 2) * BSTRIDE + kk] = u4.z;
          lbuf[(c16 + j4 * 4 + 3) * BSTRIDE + kk] = u4.w;
        }
      }
    }
  }
  __syncthreads();
  int wv = threadIdx.x >> 6, lane = threadIdx.x & 63;
  int quad = lane >> 4, li = lane & 15;
  int wm = wv >> 1, wn = wv & 1;
  f32x4 acc[2][2];
#pragma unroll
  for (int a = 0; a < 2; a++)
#pragma unroll
    for (int b = 0; b < 2; b++) acc[a][b] = (f32x4){0.f, 0.f, 0.f, 0.f};
#pragma unroll
  for (int ks = 0; ks < 10; ++ks) {
    short8 af[2], bfrag[2];
#pragma unroll
    for (int mt = 0; mt < 2; ++mt) {
      long r = m0 + wm * 32 + mt * 16 + li;
      if (r > N_TOK - 1) r = N_TOK - 1;
      af[mt] = load_afrag(x, r, ks * 32 + quad * 8, isbf);
    }
#pragma unroll
    for (int nt = 0; nt < 2; ++nt) {
      int nr = wn * 32 + nt * 16 + li;
      bfrag[nt] = *(const short8*)&lbuf[nr * BSTRIDE + ks * 32 + quad * 8];
    }
#pragma unroll
    for (int mt = 0; mt < 2; ++mt)
#pragma unroll
      for (int nt = 0; nt < 2; ++nt)
        acc[mt][nt] = __builtin_amdgcn_mfma_f32_16x16x32_bf16(af[mt], bfrag[nt], acc[mt][nt], 0, 0, 0);
  }
  __syncthreads();                     // done reading lbuf as B
  unsigned short (*ct)[68] = (unsigned short(*)[68])lbuf;   // alias as C-tile
  const float qs = (wsel == 0) ? 0.15811388300841898f * 1.4426950408889634f : 1.0f;
#pragma unroll
  for (int mt = 0; mt < 2; ++mt)
#pragma unroll
    for (int nt = 0; nt < 2; ++nt)
#pragma unroll
      for (int r = 0; r < 4; ++r)
        ct[wm * 32 + mt * 16 + quad * 4 + r][wn * 32 + nt * 16 + li] =
            bfbits(acc[mt][nt][r] * qs);
  __syncthreads();
  int kt = m0 >> 6;
  if (wsel == 0) {                     // q row-major [h][tok][40]
    int row = threadIdx.x >> 2, c4 = threadIdx.x & 3;
    int grow = m0 + row;
    if (grow < N_TOK) {
#pragma unroll
      for (int i = 0; i < 4; ++i) {
        int cg = c4 + i * 4;           // 4-col chunk; 4|40 -> never crosses a head
        int col = n_in + cg * 4;
        int h = col / DH, d = col % DH;
        ushort4 pk = *(const ushort4*)&ct[row][cg * 4];
        *(ushort4*)(q + (long)h * N_TOK * DH + (long)grow * DH + d) = pk;
      }
    }
  } else if (wsel == 1) {              // K fragment layout (8-d runs never cross 64-col tile)
#pragma unroll
    for (int rep = 0; rep < 2; ++rep) {
      int u = threadIdx.x + rep * 256;
      int row = u >> 3, c8 = (u & 7) * 8;
      int gcol = n_in + c8;
      int h = gcol / DH, d0 = gcol % DH;          // d0 in {0,8,16,24,32}
      int li2 = row & 15, nt2 = row >> 4;
      long base = (((long)h * 65 + kt) * 4 + nt2) * 640 +
                  (d0 < 32 ? ((d0 >> 3) * 16 + li2) * 8 : 512 + li2 * 8);
      ushort4 a = *(const ushort4*)&ct[row][c8];
      ushort4 b = *(const ushort4*)&ct[row][c8 + 4];
      *(ushort4*)(kswz + base) = a;
      *(ushort4*)(kswz + base + 4) = b;
    }
  } else {                             // V fragment layout (8-tok octets, column gather)
#pragma unroll
    for (int rep = 0; rep < 2; ++rep) {
      int u = threadIdx.x + rep * 256;
      int g = u & 7, dcol = u >> 3;
      int gcol = n_in + dcol;
      int h = gcol / DH, d = gcol % DH;
      int dt = d >> 4, li2 = d & 15, ksv = g >> 2, q2 = g & 3;
      union { unsigned short e[8]; ushort4 v[2]; } o;
#pragma unroll
      for (int j = 0; j < 8; ++j) o.e[j] = ct[g * 8 + j][dcol];
      long base = (((long)h * 65 + kt) * 6 + ksv * 3 + dt) * 512 + (q2 * 16 + li2) * 8;
      *(ushort4*)(vswz + base) = o.v[0];
      *(ushort4*)(vswz + base + 4) = o.v[1];
    }
  }
}

// ---------- split-K flash attention: static-max softmax, 32 q-rows/wave,
// 4-wave blocks, single P buffer, SPLITS=8 for block supply ----------
__global__ __launch_bounds__(256, 3) void attn_kernel(
    const bf16* __restrict__ qg, const bf16* __restrict__ kswz, const bf16* __restrict__ vswz,
    const unsigned short* __restrict__ awA, const unsigned short* __restrict__ bwB,
    float* __restrict__ opart, float* __restrict__ lpart) {
  __shared__ unsigned short pbuf[4][32][68];   // wave, row, col (single buffer)
  int bid = blockIdx.x;
  int h = bid & 7;
  int sp = (bid >> 3) & 7;             // 0..7
  int qt = bid >> 6;                   // 0..32 (128 q-rows per block)
  int kt0 = (sp * 65) >> 3;
  int kt1 = ((sp + 1) * 65) >> 3;
  int wv = threadIdx.x >> 6, lane = threadIdx.x & 63;
  int quad = lane >> 4, li = lane & 15;
  const bf16* qh = qg + h * (N_TOK * DH);
  const bf16* kz = kswz + (long)h * 65 * 2560;
  const bf16* vz = vswz + (long)h * 65 * 3072;

  int qrow_base = qt * 128 + wv * 32;  // up to 4223 < N_SP (awA/opart padded)
  short8 qa0[2], qa1[2];
  unsigned int aw[2][4]; int qi[2][4];
#pragma unroll
  for (int mt = 0; mt < 2; ++mt) {
    int qr = qrow_base + mt * 16 + li; if (qr > N_TOK - 1) qr = N_TOK - 1;
    qa0[mt] = *(const short8*)(qh + qr * DH + quad * 8);
    qa1[mt] = (quad == 0) ? *(const short8*)(qh + qr * DH + 32) : (short8)(__bf16)0.0f;
#pragma unroll
    for (int r = 0; r < 4; ++r) {
      qi[mt][r] = qrow_base + mt * 16 + quad * 4 + r;
      aw[mt][r] = awA[qi[mt][r]];      // padded rows -> 0 -> fully masked -> o=l=0
    }
  }

  f32x4 o[2][3];
#pragma unroll
  for (int mt = 0; mt < 2; ++mt)
#pragma unroll
    for (int d = 0; d < 3; ++d) o[mt][d] = (f32x4){0.f, 0.f, 0.f, 0.f};
  const f32x4 cm8 = (f32x4){-8.f, -8.f, -8.f, -8.f};   // static softmax shift
  int dkt = qrow_base >> 6;            // the single ktile containing this wave's diagonal

  for (int kt = kt0; kt < kt1; ++kt) {
    const bf16* kb_base = kz + (long)kt * 2560;
    f32x4 s[2][4];
    unsigned int bw[4];
#pragma unroll
    for (int nt = 0; nt < 4; ++nt) {
      bw[nt] = bwB[kt * 64 + nt * 16 + li];
      short8 kb0 = *(const short8*)(kb_base + nt * 640 + lane * 8);       // coalesced 1KB
      short8 kb1 = (quad == 0) ? *(const short8*)(kb_base + nt * 640 + 512 + li * 8)
                               : (short8)(__bf16)0.0f;
      s[0][nt] = __builtin_amdgcn_mfma_f32_16x16x32_bf16(qa0[0], kb0, cm8, 0, 0, 0);
      s[0][nt] = __builtin_amdgcn_mfma_f32_16x16x32_bf16(qa1[0], kb1, s[0][nt], 0, 0, 0);
      s[1][nt] = __builtin_amdgcn_mfma_f32_16x16x32_bf16(qa0[1], kb0, cm8, 0, 0, 0);
      s[1][nt] = __builtin_amdgcn_mfma_f32_16x16x32_bf16(qa1[1], kb1, s[1][nt], 0, 0, 0);
    }
    // V fragments (independent of P) issued before the exp phase
    short8 vb[2][3];
#pragma unroll
    for (int ksv = 0; ksv < 2; ++ksv)
#pragma unroll
      for (int dt = 0; dt < 3; ++dt)
        vb[ksv][dt] = *(const short8*)(vz + ((long)kt * 6 + ksv * 3 + dt) * 512 + lane * 8);
    // mask -> exp2 (native) -> truncation-pack bf16 -> LDS
    if (kt == dkt) {
#pragma unroll
      for (int mt = 0; mt < 2; ++mt)
#pragma unroll
        for (int nt = 0; nt < 4; ++nt)
#pragma unroll
          for (int r = 0; r < 4; ++r) {
            bool kp = ((aw[mt][r] & bw[nt]) != 0u) ||
                      (qi[mt][r] == (kt * 64 + nt * 16 + li));
            float p = EXP2F(kp ? s[mt][nt][r] : -1e5f);
            pbuf[wv][mt * 16 + quad * 4 + r][nt * 16 + li] =
                (unsigned short)(__builtin_bit_cast(unsigned int, p) >> 16);
          }
    } else {
#pragma unroll
      for (int mt = 0; mt < 2; ++mt)
#pragma unroll
        for (int nt = 0; nt < 4; ++nt)
#pragma unroll
          for (int r = 0; r < 4; ++r) {
            bool kp = (aw[mt][r] & bw[nt]) != 0u;
            float p = EXP2F(kp ? s[mt][nt][r] : -1e5f);
            pbuf[wv][mt * 16 + quad * 4 + r][nt * 16 + li] =
                (unsigned short)(__builtin_bit_cast(unsigned int, p) >> 16);
          }
    }
    // PV: P (A-layout, own wave's LDS region; compiler inserts lgkmcnt) x V fragments.
    // vswz dt=2 col d=40 is all-ones -> o[mt][2] lane li==8 accumulates l for free.
#pragma unroll
    for (int ksv = 0; ksv < 2; ++ksv) {
      union { short8 v; ushort4 u[2]; } fp[2];
#pragma unroll
      for (int mt = 0; mt < 2; ++mt) {
        fp[mt].u[0] = *(const ushort4*)&pbuf[wv][mt * 16 + li][ksv * 32 + quad * 8];
        fp[mt].u[1] = *(const ushort4*)&pbuf[wv][mt * 16 + li][ksv * 32 + quad * 8 + 4];
      }
#pragma unroll
      for (int dt = 0; dt < 3; ++dt) {
        o[0][dt] = __builtin_amdgcn_mfma_f32_16x16x32_bf16(fp[0].v, vb[ksv][dt], o[0][dt], 0, 0, 0);
        o[1][dt] = __builtin_amdgcn_mfma_f32_16x16x32_bf16(fp[1].v, vb[ksv][dt], o[1][dt], 0, 0, 0);
      }
    }
  }
  long pb2 = (long)(sp * 8 + h) * N_SP;
#pragma unroll
  for (int mt = 0; mt < 2; ++mt) {
#pragma unroll
    for (int dt = 0; dt < 3; ++dt) {
      int d = dt * 16 + li;
      if (d < DH) {
#pragma unroll
        for (int r = 0; r < 4; ++r)
          opart[(pb2 + qi[mt][r]) * DH + d] = o[mt][dt][r];
      }
    }
    if (li == 8) {
#pragma unroll
      for (int r = 0; r < 4; ++r) lpart[pb2 + qi[mt][r]] = o[mt][2][r];
    }
  }
}

// ---------- combine partials across splits (equal weights), float4-vectorized ----------
__global__ __launch_bounds__(256) void combine_kernel(
    const float* __restrict__ opart, const float* __restrict__ lpart,
    bf16* __restrict__ attn) {
  int id = blockIdx.x * 256 + threadIdx.x;   // (h, row, d4): 8*4128*10
  if (id >= 8 * N_TOK * 10) return;
  int d4 = id % 10;
  int rw = (id / 10) % N_TOK;
  int h = id / (10 * N_TOK);
  float4 osum = make_float4(0.f, 0.f, 0.f, 0.f);
  float lsum = 0.f;
#pragma unroll
  for (int s = 0; s < SPLITS; ++s) {
    long rb = (long)(s * 8 + h) * N_SP + rw;
    float4 ov = *(const float4*)(opart + rb * DH + d4 * 4);
    osum.x += ov.x; osum.y += ov.y; osum.z += ov.z; osum.w += ov.w;
    lsum += lpart[rb];
  }
  float rl = 1.0f / fmaxf(lsum, 1e-30f);
  union { short4 s4; unsigned short hh[4]; } u;
  u.hh[0] = bfbits(osum.x * rl); u.hh[1] = bfbits(osum.y * rl);
  u.hh[2] = bfbits(osum.z * rl); u.hh[3] = bfbits(osum.w * rl);
  *(short4*)(attn + rw * QD + h * DH + d4 * 4) = u.s4;
}

// ---------- output projection + bias (LDS-staged B from raw Wo, self-sniff) ----------
__global__ __launch_bounds__(256) void gemm_out(
    const bf16* __restrict__ A, const void* __restrict__ Wo,
    const void* __restrict__ bias, const void* __restrict__ att,
    void* __restrict__ out) {
  bool isbf = blk_sniff((const unsigned short*)att, 256);
  __shared__ unsigned short lbuf[64 * BSTRIDE];
  int m0 = blockIdx.x * 64;
  int n0 = blockIdx.y * 64;
  {
    int krow0 = threadIdx.x >> 2;
    int c16 = (threadIdx.x & 3) * 16;
#pragma unroll
    for (int it = 0; it < 5; ++it) {
      int kk = it * 64 + krow0;
      if (!isbf) {
        const float* wp = (const float*)Wo + (long)kk * QD + n0 + c16;
        float4 f0 = *(const float4*)wp,     f1 = *(const float4*)(wp + 4);
        float4 f2 = *(const float4*)(wp + 8), f3 = *(const float4*)(wp + 12);
        float fv[16] = {f0.x, f0.y, f0.z, f0.w, f1.x, f1.y, f1.z, f1.w,
                        f2.x, f2.y, f2.z, f2.w, f3.x, f3.y, f3.z, f3.w};
#pragma unroll
        for (int j = 0; j < 16; ++j) lbuf[(c16 + j) * BSTRIDE + kk] = bfbits(fv[j]);
      } else {
        const unsigned short* wp = (const unsigned short*)Wo + (long)kk * QD + n0 + c16;
#pragma unroll
        for (int j4 = 0; j4 < 4; ++j4) {
          ushort4 u4 = *(const ushort4*)(wp + j4 * 4);
          lbuf[(c16 + j4 * 4 + 0) * BSTRIDE + kk] = u4.x;
          lbuf[(c16 + j4 * 4 + 1) * BSTRIDE + kk] = u4.y;
          lbuf[(c16 + j4 * 4 + 2) * BSTRIDE + kk] = u4.z;
          lbuf[(c16 + j4 * 4 + 3) * BSTRIDE + kk] = u4.w;
        }
      }
    }
  }
  __syncthreads();
  int wv = threadIdx.x >> 6, lane = threadIdx.x & 63;
  int quad = lane >> 4, li = lane & 15;
  int wm = wv >> 1, wn = wv & 1;
  f32x4 acc[2][2];
#pragma unroll
  for (int a = 0; a < 2; a++)
#pragma unroll
    for (int b = 0; b < 2; b++) acc[a][b] = (f32x4){0.f, 0.f, 0.f, 0.f};
#pragma unroll
  for (int ks = 0; ks < 10; ++ks) {
    short8 af[2], bfrag[2];
#pragma unroll
    for (int mt = 0; mt < 2; ++mt) {
      int r = m0 + wm * 32 + mt * 16 + li;
      r = r < N_TOK ? r : N_TOK - 1;
      af[mt] = *(const short8*)(A + r * QD + ks * 32 + quad * 8);
    }
#pragma unroll
    for (int nt = 0; nt < 2; ++nt) {
      int nr = wn * 32 + nt * 16 + li;
      bfrag[nt] = *(const short8*)&lbuf[nr * BSTRIDE + ks * 32 + quad * 8];
    }
#pragma unroll
    for (int mt = 0; mt < 2; ++mt)
#pragma unroll
      for (int nt = 0; nt < 2; ++nt)
        acc[mt][nt] = __builtin_amdgcn_mfma_f32_16x16x32_bf16(af[mt], bfrag[nt], acc[mt][nt], 0, 0, 0);
  }
#pragma unroll
  for (int mt = 0; mt < 2; ++mt)
#pragma unroll
    for (int nt = 0; nt < 2; ++nt)
#pragma unroll
      for (int r = 0; r < 4; ++r) {
        int row = m0 + wm * 32 + mt * 16 + quad * 4 + r;
        if (row >= N_TOK) continue;
        int col = n0 + wn * 32 + nt * 16 + li;
        float val = acc[mt][nt][r] + loadS(bias, col, isbf);
        if (isbf) ((bf16*)out)[row * QD + col] = (bf16)val;
        else      ((float*)out)[row * QD + col] = val;
      }
}

extern "C" void kernel_launch(void* const* d_in, const int* in_sizes, int n_in,
                              void* d_out, int out_size, void* d_ws, size_t ws_size,
                              hipStream_t stream) {
  (void)in_sizes; (void)n_in; (void)out_size; (void)ws_size;
  const void* x   = d_in[0];
  const void* att = d_in[1];
  const void* Wq  = d_in[2];
  const void* Wk  = d_in[3];
  const void* Wv  = d_in[4];
  const void* Wo  = d_in[5];
  const void* bo  = d_in[6];
  char* ws = (char*)d_ws;
  unsigned short* awA = (unsigned short*)(ws + 0);        // 8448
  unsigned short* bwB = (unsigned short*)(ws + 8704);     // 8448
  bf16* qb    = (bf16*)(ws + 17408);                      // 2641920
  bf16* kswz  = (bf16*)(ws + 2659328);                    // 2662400
  bf16* vswz  = (bf16*)(ws + 5321728);                    // 3194880
  bf16* attnb = (bf16*)(ws + 8516608);                    // 2641920
  float* opart = (float*)(ws + 11158528);                 // 8 splits: 43253760
  float* lpart = (float*)(ws + 54412288);                 // 1081344 -> total 55493632

  dim3 g1(65, 16);   // by 0..14 = GEMM tiles, by 15 = masks + vswz ones
  qkv_mega<<<g1, 256, 0, stream>>>(x, att, Wq, Wk, Wv, qb, kswz, vswz, awA, bwB);
  attn_kernel<<<33 * SPLITS * 8, 256, 0, stream>>>(qb, kswz, vswz, awA, bwB, opart, lpart);
  combine_kernel<<<(8 * N_TOK * 10 + 255) / 256, 256, 0, stream>>>(opart, lpart, attnb);
  dim3 g2(65, 5);
  gemm_out<<<g2, 256, 0, stream>>>(attnb, Wo, bo, att, d_out);
}